// Round 1
// baseline (111.188 us; speedup 1.0000x reference)
//
#include <hip/hip_runtime.h>

// Exactness: selection (pos/neg thresholds, argmax ties) must match the numpy
// f32 reference bit-for-bit. Disable FMA contraction so "sum - a*b" is not
// fused differently than numpy evaluates it.
#pragma clang fp contract(off)

#define GMAX 256

// Kernel 1: per-RoI max-IoU + argmax over GTs, classify pos/neg.
// Output per roi (int): argmax_gt (low 16 bits) | pos<<16 | neg<<17
__global__ __launch_bounds__(256) void iou_cls_kernel(
    const float* __restrict__ rois, const float* __restrict__ gts,
    int* __restrict__ cls_out, int R, int G)
{
    const int bi = blockIdx.y;
    const int r  = blockIdx.x * 256 + threadIdx.x;

    __shared__ float gy1[GMAX], gx1[GMAX], gy2[GMAX], gx2[GMAX], gar[GMAX];
    __shared__ int   gval[GMAX];

    const int t = threadIdx.x;
    if (t < G && t < GMAX) {
        const float4 g4 = *reinterpret_cast<const float4*>(gts + ((size_t)bi * G + t) * 4);
        const float s = 1.0f / 1024.0f;   // /1024 is exact (power of two)
        const float a = g4.x * s, b = g4.y * s, c = g4.z * s, d = g4.w * s;
        gy1[t] = a; gx1[t] = b; gy2[t] = c; gx2[t] = d;
        gval[t] = (a != 0.f) || (b != 0.f) || (c != 0.f) || (d != 0.f);
        gar[t] = fmaxf(c - a, 0.f) * fmaxf(d - b, 0.f);
    }
    __syncthreads();
    if (r >= R) return;

    const float4 rr = *reinterpret_cast<const float4*>(rois + ((size_t)bi * R + r) * 4);
    const bool rv = (rr.x != 0.f) || (rr.y != 0.f) || (rr.z != 0.f) || (rr.w != 0.f);
    const float ar = fmaxf(rr.z - rr.x, 0.f) * fmaxf(rr.w - rr.y, 0.f);

    float best = -1.0f;
    int   bidx = 0;
    #pragma unroll 4
    for (int g = 0; g < G; ++g) {
        // identical op order to reference _iou_matrix
        const float y1 = fmaxf(rr.x, gy1[g]);
        const float x1 = fmaxf(rr.y, gx1[g]);
        const float y2 = fminf(rr.z, gy2[g]);
        const float x2 = fminf(rr.w, gx2[g]);
        const float inter = fmaxf(y2 - y1, 0.f) * fmaxf(x2 - x1, 0.f);
        const float uni   = (ar + gar[g]) - inter;
        float iou = inter / fmaxf(uni, 1e-7f);   // IEEE f32 divide
        if (!gval[g]) iou = -1.0f;
        if (iou > best) { best = iou; bidx = g; }   // strict > = first-occurrence argmax
    }

    const int pos = (rv && (best >= 0.5f)) ? 1 : 0;
    const int neg = (rv && (best < 0.5f) && (best >= 0.1f)) ? 1 : 0;
    cls_out[(size_t)bi * R + r] = (bidx & 0xFFFF) | (pos << 16) | (neg << 17);
}

// Kernel 2: per-image ordered selection (first 16 pos / first 64 neg by index)
// + compute the 64 output slots.
__global__ __launch_bounds__(1024) void select_kernel(
    const float* __restrict__ rois, const float* __restrict__ gts,
    const int* __restrict__ labels, const int* __restrict__ cls,
    float* __restrict__ out, int R, int G, int B)
{
    const int bi  = blockIdx.x;
    const int tid = threadIdx.x;
    const int* clsb = cls + (size_t)bi * R;

    // segment-contiguous assignment preserves ascending-index order
    const int seg = (R + 1023) >> 10;
    const int s0 = tid * seg;
    const int s1 = min(R, s0 + seg);

    int pc = 0, nc = 0;
    for (int r = s0; r < s1; ++r) {
        const int c = clsb[r];
        pc += (c >> 16) & 1;
        nc += (c >> 17) & 1;
    }

    __shared__ int sp[1024], sn[1024];
    sp[tid] = pc; sn[tid] = nc;
    __syncthreads();
    // Hillis-Steele inclusive scan
    for (int off = 1; off < 1024; off <<= 1) {
        const int vp = (tid >= off) ? sp[tid - off] : 0;
        const int vn = (tid >= off) ? sn[tid - off] : 0;
        __syncthreads();
        sp[tid] += vp; sn[tid] += vn;
        __syncthreads();
    }
    const int pbase = sp[tid] - pc;
    const int nbase = sn[tid] - nc;
    const int tot_p = sp[1023];
    const int tot_n = sn[1023];

    __shared__ int plist[16], nlist[64];
    if (tid < 16) plist[tid] = 0;
    if (tid < 64) nlist[tid] = 0;
    __syncthreads();

    if ((pbase < 16 && pc > 0) || (nbase < 64 && nc > 0)) {
        int p = pbase, n = nbase;
        for (int r = s0; r < s1; ++r) {
            const int c = clsb[r];
            if ((c >> 16) & 1) { if (p < 16) plist[p] = r; ++p; }
            if ((c >> 17) & 1) { if (n < 64) nlist[n] = r; ++n; }
        }
    }
    __syncthreads();

    const int n_pos = min(tot_p, 16);
    const int n_neg = min(tot_n, 64 - n_pos);

    if (tid < 64) {
        const int slot = tid;
        const bool isp = slot < n_pos;
        const bool isn = (!isp) && (slot < n_pos + n_neg);
        const int pidx = plist[min(slot, 15)];
        const int nidx = nlist[max(0, min(slot - n_pos, 63))];
        const int ridx = isp ? pidx : (isn ? nidx : 0);

        const float4 rr = *reinterpret_cast<const float4*>(rois + ((size_t)bi * R + ridx) * 4);
        const int gidx = clsb[ridx] & 0xFFFF;
        const float4 g4 = *reinterpret_cast<const float4*>(gts + ((size_t)bi * G + gidx) * 4);
        const float s = 1.0f / 1024.0f;
        const float g0 = g4.x * s, g1 = g4.y * s, g2 = g4.z * s, g3 = g4.w * s;

        const float vf = (isp || isn) ? 1.0f : 0.0f;
        const float eps = 1e-7f;

        const float rh  = fmaxf(rr.z - rr.x, eps);
        const float rw  = fmaxf(rr.w - rr.y, eps);
        const float rcy = rr.x + 0.5f * rh;
        const float rcx = rr.y + 0.5f * rw;
        const float gh  = fmaxf(g2 - g0, eps);
        const float gw  = fmaxf(g3 - g1, eps);
        const float gcy = g0 + 0.5f * gh;
        const float gcx = g1 + 0.5f * gw;

        float o0 = (gcy - rcy) / rh;
        float o1 = (gcx - rcx) / rw;
        float o2 = logf(gh / rh);
        float o3 = logf(gw / rw);
        // reference: (offsets * vf) / BBOX_STD
        o0 = (o0 * vf) / 0.1f;
        o1 = (o1 * vf) / 0.1f;
        o2 = (o2 * vf) / 0.2f;
        o3 = (o3 * vf) / 0.2f;

        const int base = bi * 64 + slot;
        float4* out_roi = reinterpret_cast<float4*>(out) + base;
        float4* out_off = reinterpret_cast<float4*>(out + (size_t)B * 256) + base;
        *out_roi = make_float4(rr.x * vf, rr.y * vf, rr.z * vf, rr.w * vf);
        *out_off = make_float4(o0, o1, o2, o3);

        const float lab = isp ? (float)labels[(size_t)bi * G + gidx] : 0.0f;
        out[(size_t)B * 512 + base] = lab;
    }
}

extern "C" void kernel_launch(void* const* d_in, const int* in_sizes, int n_in,
                              void* d_out, int out_size, void* d_ws, size_t ws_size,
                              hipStream_t stream)
{
    const float* rois   = (const float*)d_in[0];
    const float* gts    = (const float*)d_in[1];
    const int*   labels = (const int*)d_in[2];
    float* out = (float*)d_out;

    const int B = out_size / 576;            // 64*4 + 64*4 + 64 per image
    const int G = in_sizes[2] / B;
    const int R = in_sizes[0] / (4 * B);

    int* cls = (int*)d_ws;                   // B*R ints

    dim3 gridA((R + 255) / 256, B);
    iou_cls_kernel<<<gridA, 256, 0, stream>>>(rois, gts, cls, R, G);
    select_kernel<<<B, 1024, 0, stream>>>(rois, gts, labels, cls, out, R, G, B);
}